// Round 5
// baseline (36.936 us; speedup 1.0000x reference)
//
#include <hip/hip_runtime.h>
#include <hip/hip_bf16.h>
#include <math.h>

#define T_   4096
#define E_   256
#define H_   4
#define HD_  64

typedef __attribute__((ext_vector_type(8))) short short8;
typedef __attribute__((ext_vector_type(4))) float f32x4;
typedef unsigned int u32;
typedef unsigned short ushort_t;

typedef const __attribute__((address_space(1))) u32* gas_ptr;
typedef __attribute__((address_space(3))) u32* las_ptr;

__device__ __forceinline__ void gld_lds16(const void* g, void* l) {
    __builtin_amdgcn_global_load_lds((gas_ptr)g, (las_ptr)l, 16, 0, 0);
}

__device__ __forceinline__ ushort_t f2bf(float f) {
    __hip_bfloat16 h = __float2bfloat16(f);
    return *reinterpret_cast<ushort_t*>(&h);
}

__device__ __forceinline__ short8 pack8(float4 a, float4 b) {
    short8 p;
    p[0] = (short)f2bf(a.x); p[1] = (short)f2bf(a.y);
    p[2] = (short)f2bf(a.z); p[3] = (short)f2bf(a.w);
    p[4] = (short)f2bf(b.x); p[5] = (short)f2bf(b.y);
    p[6] = (short)f2bf(b.z); p[7] = (short)f2bf(b.w);
    return p;
}

// -------------------- MFMA GEMM, r2 double-buffered structure ----------------
// MODE 0 (qkv): A = x fp32 (reg-stage + cvt), B = Wqkv fp32 (reg-stage + cvt),
//               MF=2 (128-row M-tile), scatter epilogue to bf16 q/k/v.
// MODE 1 (proj): A = aob bf16 (async global_load_lds), B = Wout fp32
//               (reg-stage + cvt), MF=1 (64-row M-tile), fp32 out + bias.
template<int MODE, int MF>
__global__ __launch_bounds__(256) void gemm_kernel(
    const void* __restrict__ Ain, const float* __restrict__ Bw,
    const float* __restrict__ bias,
    ushort_t* __restrict__ o0, ushort_t* __restrict__ o1, ushort_t* __restrict__ o2,
    float* __restrict__ of)
{
    constexpr bool CVTA = (MODE == 0);
    __shared__ __align__(16) char As[2][MF * 8192];   // [MF*64][64] bf16, swz
    __shared__ __align__(16) char Bs[2][8192];        // [64][64] bf16, swz
    const int tid  = threadIdx.x;
    const int lane = tid & 63;
    const int wid  = tid >> 6;
    const int m0   = blockIdx.y * (MF * 64);
    const int bx   = blockIdx.x;
    const int n0   = bx * 64;
    const int ln   = lane & 15;
    const int lg   = lane >> 4;

    float4 ar[MF][4];     // A fp32 chunks (CVTA only)
    float4 br[4];         // B fp32 chunks

    auto load_regs = [&](int ks) {                    // issue global loads
        const int k0 = ks * 64;
        if constexpr (CVTA) {
            #pragma unroll
            for (int c = 0; c < MF; ++c) {
                int u = c * 256 + tid;
                int row = u >> 2, kq = u & 3;
                const float4* s = (const float4*)((const float*)Ain
                                   + (size_t)(m0 + row) * 256 + k0 + kq * 16);
                ar[c][0] = s[0]; ar[c][1] = s[1]; ar[c][2] = s[2]; ar[c][3] = s[3];
            }
        }
        int row = tid >> 2, kq = tid & 3;
        const float4* s = (const float4*)(Bw + (size_t)(n0 + row) * 256 + k0 + kq * 16);
        br[0] = s[0]; br[1] = s[1]; br[2] = s[2]; br[3] = s[3];
    };

    auto stage_A_lds = [&](int buf, int ks) {         // bf16 A via async DMA
        #pragma unroll
        for (int i = 0; i < MF * 2; ++i) {
            int u   = wid * (MF * 2) + i;
            int o   = u * 1024 + lane * 16;
            int row = o >> 7;
            int cb  = o & 127;
            int sc  = cb ^ ((row & 7) << 4);
            gld_lds16((const char*)Ain + (size_t)(m0 + row) * 512 + ks * 128 + sc,
                      &As[buf][u * 1024]);
        }
    };

    auto write_lds = [&](int buf) {                   // cvt + swizzled ds_write
        if constexpr (CVTA) {
            #pragma unroll
            for (int c = 0; c < MF; ++c) {
                int u = c * 256 + tid;
                int row = u >> 2, kq = u & 3;
                int bb = kq * 32, sw = (row & 7) << 4;
                *(short8*)(&As[buf][row * 128 + (bb ^ sw)])        = pack8(ar[c][0], ar[c][1]);
                *(short8*)(&As[buf][row * 128 + ((bb + 16) ^ sw)]) = pack8(ar[c][2], ar[c][3]);
            }
        }
        int row = tid >> 2, kq = tid & 3;
        int bb = kq * 32, sw = (row & 7) << 4;
        *(short8*)(&Bs[buf][row * 128 + (bb ^ sw)])        = pack8(br[0], br[1]);
        *(short8*)(&Bs[buf][row * 128 + ((bb + 16) ^ sw)]) = pack8(br[2], br[3]);
    };

    f32x4 acc[MF][4];
    #pragma unroll
    for (int i = 0; i < MF; ++i)
        #pragma unroll
        for (int j = 0; j < 4; ++j)
            acc[i][j] = (f32x4){0.f, 0.f, 0.f, 0.f};

    auto compute = [&](int buf) {
        #pragma unroll
        for (int k2 = 0; k2 < 2; ++k2) {
            short8 af[MF], bfr[4];
            #pragma unroll
            for (int mf = 0; mf < MF; ++mf) {
                int row = wid * (16 * MF) + mf * 16 + ln;
                int off = (k2 * 64 + lg * 16) ^ ((row & 7) << 4);
                af[mf] = *(const short8*)(&As[buf][row * 128 + off]);
            }
            #pragma unroll
            for (int nf = 0; nf < 4; ++nf) {
                int row = nf * 16 + ln;
                int off = (k2 * 64 + lg * 16) ^ ((row & 7) << 4);
                bfr[nf] = *(const short8*)(&Bs[buf][row * 128 + off]);
            }
            #pragma unroll
            for (int mf = 0; mf < MF; ++mf)
                #pragma unroll
                for (int nf = 0; nf < 4; ++nf)
                    acc[mf][nf] = __builtin_amdgcn_mfma_f32_16x16x32_bf16(
                        af[mf], bfr[nf], acc[mf][nf], 0, 0, 0);
        }
    };

    load_regs(0);
    if constexpr (!CVTA) stage_A_lds(0, 0);
    write_lds(0);
    __syncthreads();
    #pragma unroll
    for (int t = 0; t < 4; ++t) {
        if (t < 3) {
            load_regs(t + 1);
            if constexpr (!CVTA) stage_A_lds((t + 1) & 1, t + 1);
        }
        compute(t & 1);
        if (t < 3) write_lds((t + 1) & 1);
        __syncthreads();
    }

    // epilogue: C-layout m = m0 + wid*16*MF + mf*16 + lg*4 + r, n = n0 + nf*16 + ln
    if (MODE == 0) {
        const int which = bx >> 2;              // 0=q 1=k 2=v (uniform per block)
        const int h     = bx & 3;
        ushort_t* dst = (which == 0) ? o0 : (which == 1) ? o1 : o2;
        const float scale = (which == 0) ? 0.125f : 1.0f;
        #pragma unroll
        for (int nf = 0; nf < 4; ++nf) {
            int d = nf * 16 + ln;
            float bv = bias[n0 + d];
            #pragma unroll
            for (int mf = 0; mf < MF; ++mf)
                #pragma unroll
                for (int r = 0; r < 4; ++r) {
                    int m  = m0 + wid * (16 * MF) + mf * 16 + lg * 4 + r;
                    int bb = m >> 12;
                    int t  = m & (T_ - 1);
                    float v = (acc[mf][nf][r] + bv) * scale;
                    dst[((size_t)(bb * H_ + h) * T_ + t) * HD_ + d] = f2bf(v);
                }
        }
    } else {
        #pragma unroll
        for (int nf = 0; nf < 4; ++nf) {
            int n = n0 + nf * 16 + ln;
            float bv = bias[n];
            #pragma unroll
            for (int mf = 0; mf < MF; ++mf)
                #pragma unroll
                for (int r = 0; r < 4; ++r) {
                    int m = m0 + wid * (16 * MF) + mf * 16 + lg * 4 + r;
                    of[(size_t)m * E_ + n] = acc[mf][nf][r] + bv;
                }
        }
    }
}

// -------------------- Kernel 2: MFMA banded attention (unchanged) ------------
__global__ __launch_bounds__(256) void attn_kernel(
    const ushort_t* __restrict__ q, const ushort_t* __restrict__ k,
    const ushort_t* __restrict__ v, ushort_t* __restrict__ ao)
{
    __shared__ __align__(16) char smem[20480 + 25600];
    char* Ks = smem;            // [160][64] bf16, 128B rows, XOR swizzle
    char* Pb = smem;            // overlay: 4 waves x [16][104] bf16 (208B pitch)
    char* Vt = smem + 20480;    // [64][200] bf16 (400B pitch), k-XOR swizzle

    const int tid = threadIdx.x;
    const int bh  = blockIdx.y;
    const int t0  = blockIdx.x * 64;
    const int kbase = t0 - 32;
    const char* kb = (const char*)(k + (size_t)bh * T_ * HD_);
    const char* vb = (const char*)(v + (size_t)bh * T_ * HD_);
    const char* qb = (const char*)(q + (size_t)bh * T_ * HD_);

    int4 kreg[5], vreg[5];
    #pragma unroll
    for (int l = 0; l < 5; ++l) {
        int u = tid + l * 256;              // 0..1279 = 160 rows x 8 x 16B
        int row = u >> 3;
        int g = kbase + row;
        bool ok = (unsigned)g < (unsigned)T_;
        kreg[l] = ok ? *(const int4*)(kb + (size_t)g * 128 + (u & 7) * 16)
                     : make_int4(0, 0, 0, 0);
        vreg[l] = ok ? *(const int4*)(vb + (size_t)g * 128 + (u & 7) * 16)
                     : make_int4(0, 0, 0, 0);
    }
    #pragma unroll
    for (int l = 0; l < 5; ++l) {
        int u = tid + l * 256;
        int row = u >> 3;
        int cb = (u & 7) * 16;
        *(int4*)(Ks + row * 128 + (cb ^ ((row & 7) << 4))) = kreg[l];
        const u32* wv = (const u32*)&vreg[l];
        #pragma unroll
        for (int j = 0; j < 8; ++j) {
            int d = (u & 7) * 8 + j;
            ushort_t h = (j & 1) ? (ushort_t)(wv[j >> 1] >> 16)
                                 : (ushort_t)(wv[j >> 1] & 0xffffu);
            *(ushort_t*)(Vt + d * 400 + ((row * 2) ^ (((d >> 3) & 7) << 4))) = h;
        }
    }
    __syncthreads();

    const int wv_ = tid >> 6;               // wave 0..3
    const int ln  = tid & 15;
    const int lg  = (tid & 63) >> 4;        // lane group 0..3

    short8 qf[2];
    #pragma unroll
    for (int k2 = 0; k2 < 2; ++k2)
        qf[k2] = *(const short8*)(qb + (size_t)(t0 + wv_ * 16 + ln) * 128
                                  + k2 * 64 + lg * 16);

    f32x4 sa[6];
    #pragma unroll
    for (int nf = 0; nf < 6; ++nf) sa[nf] = (f32x4){0.f, 0.f, 0.f, 0.f};
    #pragma unroll
    for (int k2 = 0; k2 < 2; ++k2) {
        #pragma unroll
        for (int nf = 0; nf < 6; ++nf) {
            int row = wv_ * 16 + nf * 16 + ln;
            short8 kf = *(const short8*)(Ks + row * 128 +
                          ((k2 * 64 + lg * 16) ^ ((row & 7) << 4)));
            sa[nf] = __builtin_amdgcn_mfma_f32_16x16x32_bf16(qf[k2], kf, sa[nf], 0, 0, 0);
        }
    }

    const int nm0 = ln - 4 * lg;
    #pragma unroll
    for (int nf = 0; nf < 6; ++nf)
        #pragma unroll
        for (int r = 0; r < 4; ++r) {
            int diff = nm0 + 16 * nf - r;           // n - m, window iff 0..64
            if (diff < 0 || diff > 64) sa[nf][r] = -1e30f;
        }
    float inv_[4];
    #pragma unroll
    for (int r = 0; r < 4; ++r) {
        float mx = sa[0][r];
        #pragma unroll
        for (int nf = 1; nf < 6; ++nf) mx = fmaxf(mx, sa[nf][r]);
        mx = fmaxf(mx, __shfl_xor(mx, 1));
        mx = fmaxf(mx, __shfl_xor(mx, 2));
        mx = fmaxf(mx, __shfl_xor(mx, 4));
        mx = fmaxf(mx, __shfl_xor(mx, 8));
        float s = 0.f;
        #pragma unroll
        for (int nf = 0; nf < 6; ++nf) {
            float e = __expf(sa[nf][r] - mx);
            sa[nf][r] = e;
            s += e;
        }
        s += __shfl_xor(s, 1);
        s += __shfl_xor(s, 2);
        s += __shfl_xor(s, 4);
        s += __shfl_xor(s, 8);
        inv_[r] = 1.f / s;
    }

    __syncthreads();
    char* Pw = Pb + wv_ * 3328;                     // 16 rows x 208B
    #pragma unroll
    for (int nf = 0; nf < 6; ++nf)
        #pragma unroll
        for (int r = 0; r < 4; ++r)
            *(ushort_t*)(Pw + (4 * lg + r) * 208 + (16 * nf + ln) * 2)
                = f2bf(sa[nf][r]);

    f32x4 oa[4];
    #pragma unroll
    for (int nf = 0; nf < 4; ++nf) oa[nf] = (f32x4){0.f, 0.f, 0.f, 0.f};
    #pragma unroll
    for (int ks = 0; ks < 3; ++ks) {
        short8 pa = *(const short8*)(Pw + ln * 208 + ks * 64 + lg * 16);
        #pragma unroll
        for (int nf = 0; nf < 4; ++nf) {
            int d = nf * 16 + ln;
            short8 vbf = *(const short8*)(Vt + d * 400 +
                           ((32 * wv_ + 64 * ks + 16 * lg) ^ (((d >> 3) & 7) << 4)));
            oa[nf] = __builtin_amdgcn_mfma_f32_16x16x32_bf16(pa, vbf, oa[nf], 0, 0, 0);
        }
    }

    const int bb = bh >> 2, hh = bh & 3;
    #pragma unroll
    for (int nf = 0; nf < 4; ++nf)
        #pragma unroll
        for (int r = 0; r < 4; ++r) {
            int t = t0 + wv_ * 16 + 4 * lg + r;
            int d = nf * 16 + ln;
            ao[((size_t)bb * T_ + t) * E_ + hh * HD_ + d] = f2bf(oa[nf][r] * inv_[r]);
        }
}

extern "C" void kernel_launch(void* const* d_in, const int* in_sizes, int n_in,
                              void* d_out, int out_size, void* d_ws, size_t ws_size,
                              hipStream_t stream) {
    const float* x    = (const float*)d_in[0];
    const float* Wqkv = (const float*)d_in[1];
    const float* bqkv = (const float*)d_in[2];
    const float* Wout = (const float*)d_in[3];
    const float* bout = (const float*)d_in[4];
    float* out = (float*)d_out;

    char* ws = (char*)d_ws;
    ushort_t* qb  = (ushort_t*)(ws);                 // 4 MB [BH][T][64] bf16
    ushort_t* kbp = (ushort_t*)(ws + 4194304);       // 4 MB
    ushort_t* vbp = (ushort_t*)(ws + 8388608);       // 4 MB
    ushort_t* aob = (ushort_t*)(ws + 12582912);      // 4 MB [B][T][256] bf16

    gemm_kernel<0, 2><<<dim3(12, 64), 256, 0, stream>>>(
        (const void*)x, Wqkv, bqkv, qb, kbp, vbp, nullptr);
    attn_kernel<<<dim3(64, 8), 256, 0, stream>>>(qb, kbp, vbp, aob);
    gemm_kernel<1, 1><<<dim3(4, 128), 256, 0, stream>>>(
        (const void*)aob, Wout, bout, nullptr, nullptr, nullptr, out);
}

// Round 6
// 34.978 us; speedup vs baseline: 1.0560x; 1.0560x over previous
//
#include <hip/hip_runtime.h>
#include <hip/hip_bf16.h>
#include <math.h>

#define T_   4096
#define E_   256
#define H_   4
#define HD_  64

typedef __attribute__((ext_vector_type(8))) short short8;
typedef __attribute__((ext_vector_type(4))) float f32x4;
typedef unsigned int u32;
typedef unsigned short ushort_t;

typedef const __attribute__((address_space(1))) u32* gas_ptr;
typedef __attribute__((address_space(3))) u32* las_ptr;

__device__ __forceinline__ void gld_lds16(const void* g, void* l) {
    __builtin_amdgcn_global_load_lds((gas_ptr)g, (las_ptr)l, 16, 0, 0);
}

__device__ __forceinline__ ushort_t f2bf(float f) {
    __hip_bfloat16 h = __float2bfloat16(f);
    return *reinterpret_cast<ushort_t*>(&h);
}

// -------------------- Kernel 0: fp32 -> bf16 convert (x, Wqkv, Wout) ----------
__global__ __launch_bounds__(256) void cvt_kernel(
    const float* __restrict__ x, const float* __restrict__ wq,
    const float* __restrict__ wo,
    ushort_t* __restrict__ xb, ushort_t* __restrict__ wqb, ushort_t* __restrict__ wob)
{
    int idx = blockIdx.x * 256 + threadIdx.x;   // unit of 8 elems
    const float* src; ushort_t* dst; int off;
    if (idx < 262144)       { src = x;  dst = xb;  off = idx * 8; }
    else if (idx < 286720)  { src = wq; dst = wqb; off = (idx - 262144) * 8; }
    else                    { src = wo; dst = wob; off = (idx - 286720) * 8; }
    float4 a = *(const float4*)(src + off);
    float4 b = *(const float4*)(src + off + 4);
    short8 p;
    p[0] = (short)f2bf(a.x); p[1] = (short)f2bf(a.y);
    p[2] = (short)f2bf(a.z); p[3] = (short)f2bf(a.w);
    p[4] = (short)f2bf(b.x); p[5] = (short)f2bf(b.y);
    p[6] = (short)f2bf(b.z); p[7] = (short)f2bf(b.w);
    *(short8*)(dst + off) = p;
}

// -------------------- MFMA GEMM, dbuf BK=64, bf16 inputs via gld_lds ---------
// MODE 0 (qkv): MF=2 (128-row tile), scatter epilogue to bf16 q/k/v.
// MODE 1 (proj): MF=1 (64-row tile, 2 blocks/CU), fp32 out + bias.
template<int MODE, int MF>
__global__ __launch_bounds__(256) void gemm_kernel(
    const char* __restrict__ A, const char* __restrict__ Bw,
    const float* __restrict__ bias,
    ushort_t* __restrict__ o0, ushort_t* __restrict__ o1, ushort_t* __restrict__ o2,
    float* __restrict__ of)
{
    __shared__ __align__(16) char As[2][MF * 8192];   // [MF*64][64] bf16, swz
    __shared__ __align__(16) char Bs[2][8192];        // [64][64]  bf16, swz
    const int tid  = threadIdx.x;
    const int lane = tid & 63;
    const int wid  = tid >> 6;
    const int m0   = blockIdx.y * (MF * 64);
    const int bx   = blockIdx.x;
    const int n0   = bx * 64;
    const int ln   = lane & 15;
    const int lg   = lane >> 4;

    f32x4 acc[MF][4];
    #pragma unroll
    for (int i = 0; i < MF; ++i)
        #pragma unroll
        for (int j = 0; j < 4; ++j)
            acc[i][j] = (f32x4){0.f, 0.f, 0.f, 0.f};

    auto stage = [&](int buf, int ks) {
        const int kb = ks * 128;                  // byte offset within 512B row
        #pragma unroll
        for (int i = 0; i < MF * 2; ++i) {        // A: MF*8KB = MF*8 x 1KB units
            int u   = wid * (MF * 2) + i;
            int o   = u * 1024 + lane * 16;
            int row = o >> 7;
            int cb  = o & 127;
            int sc  = cb ^ ((row & 7) << 4);      // pre-swizzled global source
            gld_lds16(A + (size_t)(m0 + row) * 512 + kb + sc, &As[buf][u * 1024]);
        }
        #pragma unroll
        for (int i = 0; i < 2; ++i) {             // B: 8KB = 8 x 1KB units
            int u   = wid * 2 + i;
            int o   = u * 1024 + lane * 16;
            int row = o >> 7;
            int cb  = o & 127;
            int sc  = cb ^ ((row & 7) << 4);
            gld_lds16(Bw + (size_t)(n0 + row) * 512 + kb + sc, &Bs[buf][u * 1024]);
        }
    };

    auto compute = [&](int buf) {
        #pragma unroll
        for (int k2 = 0; k2 < 2; ++k2) {
            short8 af[MF], bfr[4];
            #pragma unroll
            for (int mf = 0; mf < MF; ++mf) {
                int row = wid * (16 * MF) + mf * 16 + ln;
                int off = (k2 * 64 + lg * 16) ^ ((row & 7) << 4);
                af[mf] = *(const short8*)(&As[buf][row * 128 + off]);
            }
            #pragma unroll
            for (int nf = 0; nf < 4; ++nf) {
                int row = nf * 16 + ln;
                int off = (k2 * 64 + lg * 16) ^ ((row & 7) << 4);
                bfr[nf] = *(const short8*)(&Bs[buf][row * 128 + off]);
            }
            #pragma unroll
            for (int mf = 0; mf < MF; ++mf)
                #pragma unroll
                for (int nf = 0; nf < 4; ++nf)
                    acc[mf][nf] = __builtin_amdgcn_mfma_f32_16x16x32_bf16(
                        af[mf], bfr[nf], acc[mf][nf], 0, 0, 0);
        }
    };

    stage(0, 0);
    __syncthreads();
    #pragma unroll
    for (int t = 0; t < 4; ++t) {
        if (t < 3) stage((t + 1) & 1, t + 1);
        compute(t & 1);
        __syncthreads();
    }

    // epilogue: C-layout m = m0 + wid*16*MF + mf*16 + lg*4 + r, n = n0 + nf*16 + ln
    if (MODE == 0) {
        const int which = bx >> 2;              // 0=q 1=k 2=v (uniform per block)
        const int h     = bx & 3;
        ushort_t* dst = (which == 0) ? o0 : (which == 1) ? o1 : o2;
        const float scale = (which == 0) ? 0.125f : 1.0f;
        #pragma unroll
        for (int nf = 0; nf < 4; ++nf) {
            int d = nf * 16 + ln;
            float bv = bias[n0 + d];
            #pragma unroll
            for (int mf = 0; mf < MF; ++mf)
                #pragma unroll
                for (int r = 0; r < 4; ++r) {
                    int m  = m0 + wid * (16 * MF) + mf * 16 + lg * 4 + r;
                    int bb = m >> 12;
                    int t  = m & (T_ - 1);
                    float v = (acc[mf][nf][r] + bv) * scale;
                    dst[((size_t)(bb * H_ + h) * T_ + t) * HD_ + d] = f2bf(v);
                }
        }
    } else {
        #pragma unroll
        for (int nf = 0; nf < 4; ++nf) {
            int n = n0 + nf * 16 + ln;
            float bv = bias[n];
            #pragma unroll
            for (int mf = 0; mf < MF; ++mf)
                #pragma unroll
                for (int r = 0; r < 4; ++r) {
                    int m = m0 + wid * (16 * MF) + mf * 16 + lg * 4 + r;
                    of[(size_t)m * E_ + n] = acc[mf][nf][r] + bv;
                }
        }
    }
}

// -------------------- Kernel 2: MFMA banded attention --------------------
// r3 structure; only change: Q fragment loads issued between the K/V global
// loads and the LDS-write loop, so their latency hides under staging instead
// of stalling after the barrier.
__global__ __launch_bounds__(256) void attn_kernel(
    const ushort_t* __restrict__ q, const ushort_t* __restrict__ k,
    const ushort_t* __restrict__ v, ushort_t* __restrict__ ao)
{
    __shared__ __align__(16) char smem[20480 + 25600];
    char* Ks = smem;            // [160][64] bf16, 128B rows, XOR swizzle
    char* Pb = smem;            // overlay: 4 waves x [16][104] bf16 (208B pitch)
    char* Vt = smem + 20480;    // [64][200] bf16 (400B pitch), k-XOR swizzle

    const int tid = threadIdx.x;
    const int bh  = blockIdx.y;
    const int t0  = blockIdx.x * 64;
    const int kbase = t0 - 32;
    const char* kb = (const char*)(k + (size_t)bh * T_ * HD_);
    const char* vb = (const char*)(v + (size_t)bh * T_ * HD_);
    const char* qb = (const char*)(q + (size_t)bh * T_ * HD_);

    const int wv_ = tid >> 6;               // wave 0..3
    const int ln  = tid & 15;
    const int lg  = (tid & 63) >> 4;        // lane group 0..3

    int4 kreg[5], vreg[5];
    #pragma unroll
    for (int l = 0; l < 5; ++l) {
        int u = tid + l * 256;              // 0..1279 = 160 rows x 8 x 16B
        int row = u >> 3;
        int g = kbase + row;
        bool ok = (unsigned)g < (unsigned)T_;
        kreg[l] = ok ? *(const int4*)(kb + (size_t)g * 128 + (u & 7) * 16)
                     : make_int4(0, 0, 0, 0);
        vreg[l] = ok ? *(const int4*)(vb + (size_t)g * 128 + (u & 7) * 16)
                     : make_int4(0, 0, 0, 0);
    }

    // Q fragments issued here: in flight while LDS writes below retire
    short8 qf[2];
    #pragma unroll
    for (int k2 = 0; k2 < 2; ++k2)
        qf[k2] = *(const short8*)(qb + (size_t)(t0 + wv_ * 16 + ln) * 128
                                  + k2 * 64 + lg * 16);

    #pragma unroll
    for (int l = 0; l < 5; ++l) {
        int u = tid + l * 256;
        int row = u >> 3;
        int cb = (u & 7) * 16;
        *(int4*)(Ks + row * 128 + (cb ^ ((row & 7) << 4))) = kreg[l];
        const u32* wv = (const u32*)&vreg[l];
        #pragma unroll
        for (int j = 0; j < 8; ++j) {
            int d = (u & 7) * 8 + j;
            ushort_t h = (j & 1) ? (ushort_t)(wv[j >> 1] >> 16)
                                 : (ushort_t)(wv[j >> 1] & 0xffffu);
            *(ushort_t*)(Vt + d * 400 + ((row * 2) ^ (((d >> 3) & 7) << 4))) = h;
        }
    }
    __syncthreads();

    f32x4 sa[6];
    #pragma unroll
    for (int nf = 0; nf < 6; ++nf) sa[nf] = (f32x4){0.f, 0.f, 0.f, 0.f};
    #pragma unroll
    for (int k2 = 0; k2 < 2; ++k2) {
        #pragma unroll
        for (int nf = 0; nf < 6; ++nf) {
            int row = wv_ * 16 + nf * 16 + ln;
            short8 kf = *(const short8*)(Ks + row * 128 +
                          ((k2 * 64 + lg * 16) ^ ((row & 7) << 4)));
            sa[nf] = __builtin_amdgcn_mfma_f32_16x16x32_bf16(qf[k2], kf, sa[nf], 0, 0, 0);
        }
    }

    const int nm0 = ln - 4 * lg;
    #pragma unroll
    for (int nf = 0; nf < 6; ++nf)
        #pragma unroll
        for (int r = 0; r < 4; ++r) {
            int diff = nm0 + 16 * nf - r;           // n - m, window iff 0..64
            if (diff < 0 || diff > 64) sa[nf][r] = -1e30f;
        }
    float inv_[4];
    #pragma unroll
    for (int r = 0; r < 4; ++r) {
        float mx = sa[0][r];
        #pragma unroll
        for (int nf = 1; nf < 6; ++nf) mx = fmaxf(mx, sa[nf][r]);
        mx = fmaxf(mx, __shfl_xor(mx, 1));
        mx = fmaxf(mx, __shfl_xor(mx, 2));
        mx = fmaxf(mx, __shfl_xor(mx, 4));
        mx = fmaxf(mx, __shfl_xor(mx, 8));
        float s = 0.f;
        #pragma unroll
        for (int nf = 0; nf < 6; ++nf) {
            float e = __expf(sa[nf][r] - mx);
            sa[nf][r] = e;
            s += e;
        }
        s += __shfl_xor(s, 1);
        s += __shfl_xor(s, 2);
        s += __shfl_xor(s, 4);
        s += __shfl_xor(s, 8);
        inv_[r] = 1.f / s;
    }

    __syncthreads();
    char* Pw = Pb + wv_ * 3328;                     // 16 rows x 208B
    #pragma unroll
    for (int nf = 0; nf < 6; ++nf)
        #pragma unroll
        for (int r = 0; r < 4; ++r)
            *(ushort_t*)(Pw + (4 * lg + r) * 208 + (16 * nf + ln) * 2)
                = f2bf(sa[nf][r]);

    f32x4 oa[4];
    #pragma unroll
    for (int nf = 0; nf < 4; ++nf) oa[nf] = (f32x4){0.f, 0.f, 0.f, 0.f};
    #pragma unroll
    for (int ks = 0; ks < 3; ++ks) {
        short8 pa = *(const short8*)(Pw + ln * 208 + ks * 64 + lg * 16);
        #pragma unroll
        for (int nf = 0; nf < 4; ++nf) {
            int d = nf * 16 + ln;
            short8 vbf = *(const short8*)(Vt + d * 400 +
                           ((32 * wv_ + 64 * ks + 16 * lg) ^ (((d >> 3) & 7) << 4)));
            oa[nf] = __builtin_amdgcn_mfma_f32_16x16x32_bf16(pa, vbf, oa[nf], 0, 0, 0);
        }
    }

    const int bb = bh >> 2, hh = bh & 3;
    #pragma unroll
    for (int nf = 0; nf < 4; ++nf)
        #pragma unroll
        for (int r = 0; r < 4; ++r) {
            int t = t0 + wv_ * 16 + 4 * lg + r;
            int d = nf * 16 + ln;
            ao[((size_t)bb * T_ + t) * E_ + hh * HD_ + d] = f2bf(oa[nf][r] * inv_[r]);
        }
}

extern "C" void kernel_launch(void* const* d_in, const int* in_sizes, int n_in,
                              void* d_out, int out_size, void* d_ws, size_t ws_size,
                              hipStream_t stream) {
    const float* x    = (const float*)d_in[0];
    const float* Wqkv = (const float*)d_in[1];
    const float* bqkv = (const float*)d_in[2];
    const float* Wout = (const float*)d_in[3];
    const float* bout = (const float*)d_in[4];
    float* out = (float*)d_out;

    char* ws = (char*)d_ws;
    ushort_t* xb  = (ushort_t*)(ws);                 // 4 MB  (8192x256)
    ushort_t* wqb = (ushort_t*)(ws + 4194304);       // 384 KB (768x256)
    ushort_t* wob = (ushort_t*)(ws + 4587520);       // 128 KB (256x256)
    ushort_t* qb  = (ushort_t*)(ws + 4718592);       // 4 MB  [BH][T][64]
    ushort_t* kbp = (ushort_t*)(ws + 8912896);       // 4 MB
    ushort_t* vbp = (ushort_t*)(ws + 13107200);      // 4 MB
    ushort_t* aob = (ushort_t*)(ws + 17301504);      // 4 MB  [B][T][256]

    cvt_kernel<<<1152, 256, 0, stream>>>(x, Wqkv, Wout, xb, wqb, wob);
    gemm_kernel<0, 2><<<dim3(12, 64), 256, 0, stream>>>(
        (const char*)xb, (const char*)wqb, bqkv, qb, kbp, vbp, nullptr);
    attn_kernel<<<dim3(64, 8), 256, 0, stream>>>(qb, kbp, vbp, aob);
    gemm_kernel<1, 1><<<dim3(4, 128), 256, 0, stream>>>(
        (const char*)aob, (const char*)wob, bout, nullptr, nullptr, nullptr, out);
}